// Round 3
// baseline (2049.975 us; speedup 1.0000x reference)
//
#include <hip/hip_runtime.h>
#include <hip/hip_bf16.h>
#include <stdint.h>

typedef __attribute__((ext_vector_type(8))) _Float16 half8;
typedef __attribute__((ext_vector_type(8))) short short8;
typedef __attribute__((ext_vector_type(4))) float floatx4;

__device__ __forceinline__ short f2h(float f) {
  _Float16 h = (_Float16)f;               // v_cvt_f16_f32, RTNE
  union { _Float16 h; short s; } u; u.h = h;
  return u.s;
}

__device__ __forceinline__ void async16(const void* g, void* l) {
  __builtin_amdgcn_global_load_lds((const __attribute__((address_space(1))) void*)g,
                                   (__attribute__((address_space(3))) void*)l, 16, 0, 0);
}

// ---------------- elementwise cast fp32 -> fp16 (layout preserved) -------------
__global__ void cast_f16_kernel(const float* __restrict__ in, short* __restrict__ out, long n) {
  long i = ((long)blockIdx.x * 256 + threadIdx.x) * 8;
  if (i >= n) return;
  const float4* p = (const float4*)(in + i);
  float4 a = p[0], b = p[1];
  short8 o = { f2h(a.x), f2h(a.y), f2h(a.z), f2h(a.w),
               f2h(b.x), f2h(b.y), f2h(b.z), f2h(b.w) };
  *(short8*)(out + i) = o;
}

// ---------------- transpose + cast: bw [R][C] fp32 -> bwT [C][R] fp16 ----------
__global__ void transpose_cast_kernel(const float* __restrict__ in, short* __restrict__ out,
                                      int R, int C) {
  __shared__ __align__(16) float t[32][33];
  int r0 = blockIdx.x * 32, c0 = blockIdx.y * 32;
  int cl = threadIdx.x & 31, rl0 = threadIdx.x >> 5;
#pragma unroll
  for (int j = 0; j < 4; ++j) {
    int rl = rl0 + 8 * j;
    t[rl][cl] = in[(long)(r0 + rl) * C + c0 + cl];
  }
  __syncthreads();
  int rl2 = threadIdx.x & 31, cl0 = threadIdx.x >> 5;
#pragma unroll
  for (int j = 0; j < 4; ++j) {
    int cl2 = cl0 + 8 * j;
    out[(long)(c0 + cl2) * R + r0 + rl2] = f2h(t[rl2][cl2]);
  }
}

// ---------------- base GEMM: silu(A[M][K] @ BT[N][K]^T) -> out fp32 [M][N] -----
template<int BN>
__global__ __launch_bounds__(256) void base_gemm_kernel(
    const short* __restrict__ A, const short* __restrict__ BT,
    float* __restrict__ out, int M, int N, int K) {
  constexpr int NI = BN / 32;
  __shared__ __align__(16) char smem[(128 + BN) * 8 * 16];
  char* As = smem;                 // slot (m, cs): (m*8+cs)*16, cs = c ^ (m&7)
  char* Bs = smem + 128 * 8 * 16;  // slot (n, cs)
  const int lane = threadIdx.x & 63, wave = threadIdx.x >> 6;
  const int wm = wave & 1, wn = wave >> 1;
  const int b0 = blockIdx.x * 128, o0 = blockIdx.y * BN;
  const int ml = lane & 15, q = lane >> 4;
  floatx4 acc[4][NI] = {};

  for (int k0 = 0; k0 < K; k0 += 64) {
#pragma unroll
    for (int j = 0; j < 4; ++j) {       // A: 1024 slots, 4 loads/wave
      int lin = wave * 256 + j * 64 + lane;
      int m = lin >> 3, cs = lin & 7;
      int cg = cs ^ (m & 7);
      const short* g = A + (long)(b0 + m) * K + k0 + cg * 8;
      async16(g, As + (wave * 256 + j * 64) * 16);
    }
#pragma unroll
    for (int j = 0; j < NI * 2; ++j) {  // B: BN*8 slots
      int lin = wave * (BN * 2) + j * 64 + lane;
      int n = lin >> 3, cs = lin & 7;
      int cg = cs ^ (n & 7);
      const short* g = BT + (long)(o0 + n) * K + k0 + cg * 8;
      async16(g, Bs + (wave * (BN * 2) + j * 64) * 16);
    }
    __syncthreads();
#pragma unroll
    for (int kk = 0; kk < 2; ++kk) {
      half8 af[4], bfv[NI];
#pragma unroll
      for (int mi = 0; mi < 4; ++mi) {
        int m = wm * 64 + mi * 16 + ml;
        int cs = (kk * 4 + q) ^ (m & 7);
        af[mi] = *(const half8*)(As + (m * 8 + cs) * 16);
      }
#pragma unroll
      for (int ni = 0; ni < NI; ++ni) {
        int n = wn * (BN / 2) + ni * 16 + ml;
        int cs = (kk * 4 + q) ^ (n & 7);
        bfv[ni] = *(const half8*)(Bs + (n * 8 + cs) * 16);
      }
#pragma unroll
      for (int mi = 0; mi < 4; ++mi)
#pragma unroll
        for (int ni = 0; ni < NI; ++ni)
          acc[mi][ni] = __builtin_amdgcn_mfma_f32_16x16x32_f16(af[mi], bfv[ni], acc[mi][ni], 0, 0, 0);
    }
    __syncthreads();
  }
#pragma unroll
  for (int mi = 0; mi < 4; ++mi)
#pragma unroll
    for (int ni = 0; ni < NI; ++ni)
#pragma unroll
      for (int r = 0; r < 4; ++r) {
        int b = b0 + wm * 64 + mi * 16 + q * 4 + r;
        int o = o0 + wn * (BN / 2) + ni * 16 + ml;
        float v = acc[mi][ni][r];
        out[(long)b * N + o] = v / (1.0f + __expf(-v));  // silu
      }
}

// ------- spline GEMM with ON-THE-FLY bases: act[M][I] fp16, swb[I][N][8] fp16 --
// acc[b][o] = sum_i sum_g exp(-3.125 (x[b][i]-cent[g])^2) * sw[i][o][g]
template<int BN>
__global__ __launch_bounds__(256) void spline_gemm_kernel(
    const short* __restrict__ act, const short* __restrict__ swb,
    const float* __restrict__ baseacc, const float* __restrict__ sb,
    const float* __restrict__ ss, float* __restrict__ outF,
    short* __restrict__ outH, int M, int N, int I) {
  constexpr int NI = BN / 32;
  __shared__ __align__(16) char smem[(128 + BN) * 8 * 16];
  char* As = smem;                 // slot (c, m): (c*128+m)*16 — 8 fp16 gaussians
  char* Bs = smem + 128 * 8 * 16;  // slot (c, n): (c*BN+n)*16
  const int lane = threadIdx.x & 63, wave = threadIdx.x >> 6;
  const int wm = wave & 1, wn = wave >> 1;
  const int b0 = blockIdx.x * 128, o0 = blockIdx.y * BN;
  const int ml = lane & 15, q = lane >> 4;
  const int am = threadIdx.x >> 1, ah = threadIdx.x & 1;   // A-staging: row, half
  const short* arow = act + (long)(b0 + am) * I + ah * 4;
  const float cent[8] = {-0.044f, -0.036f, -0.028f, -0.02f,
                         -0.012f, -0.004f,  0.004f,  0.012f};
  floatx4 acc[4][NI] = {};

  for (int i0 = 0; i0 < I; i0 += 8) {
    // B: async16 staging from swb (sw is [I][N][8] -> 16B chunk per (i,n))
#pragma unroll
    for (int j = 0; j < NI; ++j) {
      int lin = wave * (BN * 2) + j * 64;   // wave-uniform base
      int c = lin / BN, n0 = lin % BN;
      const short* g = swb + ((long)(i0 + c) * N + o0 + n0 + lane) * 8;
      async16(g, Bs + lin * 16);
    }
    // A: load 4 fp16 x-values, compute 8 gaussians each, write 4 chunks
    union { uint2 u; _Float16 h[4]; } cv;
    cv.u = *(const uint2*)(arow + i0);
    float xv[4];
#pragma unroll
    for (int t = 0; t < 4; ++t) xv[t] = (float)cv.h[t];
#pragma unroll
    for (int cl = 0; cl < 4; ++cl) {
      int c = ah * 4 + cl;
      half8 pk;
#pragma unroll
      for (int g = 0; g < 8; ++g) {
        float d = xv[cl] - cent[g];
        pk[g] = (_Float16)__builtin_exp2f(d * d * -4.5084233f);  // exp(-3.125 d^2)
      }
      *(half8*)(As + (c * 128 + am) * 16) = pk;
    }
    __syncthreads();
#pragma unroll
    for (int kk = 0; kk < 2; ++kk) {
      half8 af[4], bfv[NI];
      int c = kk * 4 + q;
#pragma unroll
      for (int mi = 0; mi < 4; ++mi)
        af[mi] = *(const half8*)(As + (c * 128 + wm * 64 + mi * 16 + ml) * 16);
#pragma unroll
      for (int ni = 0; ni < NI; ++ni)
        bfv[ni] = *(const half8*)(Bs + (c * BN + wn * (BN / 2) + ni * 16 + ml) * 16);
#pragma unroll
      for (int mi = 0; mi < 4; ++mi)
#pragma unroll
        for (int ni = 0; ni < NI; ++ni)
          acc[mi][ni] = __builtin_amdgcn_mfma_f32_16x16x32_f16(af[mi], bfv[ni], acc[mi][ni], 0, 0, 0);
    }
    __syncthreads();
  }
#pragma unroll
  for (int mi = 0; mi < 4; ++mi)
#pragma unroll
    for (int ni = 0; ni < NI; ++ni)
#pragma unroll
      for (int r = 0; r < 4; ++r) {
        int b = b0 + wm * 64 + mi * 16 + q * 4 + r;
        int o = o0 + wn * (BN / 2) + ni * 16 + ml;
        long idx = (long)b * N + o;
        float v = baseacc[idx] * sb[o] + acc[mi][ni][r] * ss[o];
        if (outF) outF[idx] = v;
        if (outH) outH[idx] = f2h(v);
      }
}

extern "C" void kernel_launch(void* const* d_in, const int* in_sizes, int n_in,
                              void* d_out, int out_size, void* d_ws, size_t ws_size,
                              hipStream_t stream) {
  const int M = 8192;
  const int Is[4] = {1024, 2048, 256, 2048};
  const int Os[4] = {2048, 256, 2048, 1024};
  const float* x = (const float*)d_in[0];
  const float* sw[4]; const float* bw[4]; const float* sb[4]; const float* ssc[4];
  for (int l = 0; l < 4; ++l) {
    sw[l]  = (const float*)d_in[1 + 5 * l];
    bw[l]  = (const float*)d_in[2 + 5 * l];
    sb[l]  = (const float*)d_in[3 + 5 * l];
    ssc[l] = (const float*)d_in[4 + 5 * l];
  }
  char* ws = (char*)d_ws;
  size_t off = 0;
  auto alloc = [&](size_t bytes) {
    char* p = ws + off; off += (bytes + 255) & ~(size_t)255; return p;
  };
  short* swb[4]; short* bwT[4];
  for (int l = 0; l < 4; ++l) swb[l] = (short*)alloc((size_t)Is[l] * Os[l] * 8 * 2);
  for (int l = 0; l < 4; ++l) bwT[l] = (short*)alloc((size_t)Is[l] * Os[l] * 2);
  short* xhf = (short*)alloc((size_t)M * 1024 * 2);
  short* hb0 = (short*)alloc((size_t)M * 2048 * 2);
  short* zb  = (short*)alloc((size_t)M * 256 * 2);
  short* hb2 = (short*)alloc((size_t)M * 2048 * 2);
  float* bacc = (float*)alloc((size_t)M * 2048 * 4);
  (void)in_sizes; (void)n_in; (void)out_size;
  if (off > ws_size) return;  // fail readable (absmax) instead of GPU fault

  // prep: cast sw to fp16 (layout preserved), transpose-cast bw, cast x
  for (int l = 0; l < 4; ++l) {
    long n = (long)Is[l] * Os[l] * 8;
    cast_f16_kernel<<<(int)(n / 2048), 256, 0, stream>>>(sw[l], swb[l], n);
    transpose_cast_kernel<<<dim3(Is[l] / 32, Os[l] / 32), 256, 0, stream>>>(bw[l], bwT[l], Is[l], Os[l]);
  }
  cast_f16_kernel<<<(int)((long)M * 1024 / 2048), 256, 0, stream>>>(x, xhf, (long)M * 1024);

  float* xrec = (float*)d_out;
  float* zout = (float*)d_out + (size_t)M * 1024;

  // layer 0: 1024 -> 2048
  base_gemm_kernel<128><<<dim3(M / 128, 2048 / 128), 256, 0, stream>>>(xhf, bwT[0], bacc, M, 2048, 1024);
  spline_gemm_kernel<128><<<dim3(M / 128, 2048 / 128), 256, 0, stream>>>(xhf, swb[0], bacc, sb[0], ssc[0], nullptr, hb0, M, 2048, 1024);

  // layer 1: 2048 -> 256 (BN=64 -> 256 blocks cover all CUs)
  base_gemm_kernel<64><<<dim3(M / 128, 256 / 64), 256, 0, stream>>>(hb0, bwT[1], bacc, M, 256, 2048);
  spline_gemm_kernel<64><<<dim3(M / 128, 256 / 64), 256, 0, stream>>>(hb0, swb[1], bacc, sb[1], ssc[1], zout, zb, M, 256, 2048);

  // layer 2: 256 -> 2048
  base_gemm_kernel<128><<<dim3(M / 128, 2048 / 128), 256, 0, stream>>>(zb, bwT[2], bacc, M, 2048, 256);
  spline_gemm_kernel<128><<<dim3(M / 128, 2048 / 128), 256, 0, stream>>>(zb, swb[2], bacc, sb[2], ssc[2], nullptr, hb2, M, 2048, 256);

  // layer 3: 2048 -> 1024
  base_gemm_kernel<128><<<dim3(M / 128, 1024 / 128), 256, 0, stream>>>(hb2, bwT[3], bacc, M, 1024, 2048);
  spline_gemm_kernel<128><<<dim3(M / 128, 1024 / 128), 256, 0, stream>>>(hb2, swb[3], bacc, sb[3], ssc[3], xrec, nullptr, M, 1024, 2048);
}

// Round 5
// 1467.750 us; speedup vs baseline: 1.3967x; 1.3967x over previous
//
#include <hip/hip_runtime.h>
#include <hip/hip_bf16.h>
#include <stdint.h>

typedef __attribute__((ext_vector_type(8))) _Float16 half8;
typedef __attribute__((ext_vector_type(2))) __fp16 fp16x2;
typedef __attribute__((ext_vector_type(8))) short short8;
typedef __attribute__((ext_vector_type(4))) float floatx4;

__device__ __forceinline__ short f2h(float f) {
  _Float16 h = (_Float16)f;               // v_cvt_f16_f32, RTNE
  union { _Float16 h; short s; } u; u.h = h;
  return u.s;
}

__device__ __forceinline__ void async16(const void* g, void* l) {
  __builtin_amdgcn_global_load_lds((const __attribute__((address_space(1))) void*)g,
                                   (__attribute__((address_space(3))) void*)l, 16, 0, 0);
}

// ---------------- elementwise cast fp32 -> fp16 (layout preserved) -------------
__global__ void cast_f16_kernel(const float* __restrict__ in, short* __restrict__ out, long n) {
  long i = ((long)blockIdx.x * 256 + threadIdx.x) * 8;
  if (i >= n) return;
  const float4* p = (const float4*)(in + i);
  float4 a = p[0], b = p[1];
  short8 o = { f2h(a.x), f2h(a.y), f2h(a.z), f2h(a.w),
               f2h(b.x), f2h(b.y), f2h(b.z), f2h(b.w) };
  *(short8*)(out + i) = o;
}

// ---------------- transpose + cast: bw [R][C] fp32 -> bwT [C][R] fp16 ----------
__global__ void transpose_cast_kernel(const float* __restrict__ in, short* __restrict__ out,
                                      int R, int C) {
  __shared__ __align__(16) float t[32][33];
  int r0 = blockIdx.x * 32, c0 = blockIdx.y * 32;
  int cl = threadIdx.x & 31, rl0 = threadIdx.x >> 5;
#pragma unroll
  for (int j = 0; j < 4; ++j) {
    int rl = rl0 + 8 * j;
    t[rl][cl] = in[(long)(r0 + rl) * C + c0 + cl];
  }
  __syncthreads();
  int rl2 = threadIdx.x & 31, cl0 = threadIdx.x >> 5;
#pragma unroll
  for (int j = 0; j < 4; ++j) {
    int cl2 = cl0 + 8 * j;
    out[(long)(c0 + cl2) * R + r0 + rl2] = f2h(t[rl2][cl2]);
  }
}

// ---------------- base GEMM: silu(A[M][K] @ BT[N][K]^T) -> out fp32 [M][N] -----
template<int BN>
__global__ __launch_bounds__(256, 4) void base_gemm_kernel(
    const short* __restrict__ A, const short* __restrict__ BT,
    float* __restrict__ out, int M, int N, int K) {
  constexpr int NI = BN / 32;
  __shared__ __align__(16) char smem[(128 + BN) * 8 * 16];
  char* As = smem;                 // slot (m, cs): (m*8+cs)*16, cs = c ^ (m&7)
  char* Bs = smem + 128 * 8 * 16;  // slot (n, cs)
  const int lane = threadIdx.x & 63, wave = threadIdx.x >> 6;
  const int wm = wave & 1, wn = wave >> 1;
  const int b0 = blockIdx.x * 128, o0 = blockIdx.y * BN;
  const int ml = lane & 15, q = lane >> 4;
  floatx4 acc[4][NI] = {};

  for (int k0 = 0; k0 < K; k0 += 64) {
#pragma unroll
    for (int j = 0; j < 4; ++j) {       // A: 1024 slots, 4 loads/wave
      int lin = wave * 256 + j * 64 + lane;
      int m = lin >> 3, cs = lin & 7;
      int cg = cs ^ (m & 7);
      const short* g = A + (long)(b0 + m) * K + k0 + cg * 8;
      async16(g, As + (wave * 256 + j * 64) * 16);
    }
#pragma unroll
    for (int j = 0; j < NI; ++j) {      // B: BN*8 slots, 2*BN chunks per wave
      int lin = wave * (BN * 2) + j * 64 + lane;
      int n = lin >> 3, cs = lin & 7;
      int cg = cs ^ (n & 7);
      const short* g = BT + (long)(o0 + n) * K + k0 + cg * 8;
      async16(g, Bs + (wave * (BN * 2) + j * 64) * 16);
    }
    __syncthreads();
#pragma unroll
    for (int kk = 0; kk < 2; ++kk) {
      half8 af[4], bfv[NI];
#pragma unroll
      for (int mi = 0; mi < 4; ++mi) {
        int m = wm * 64 + mi * 16 + ml;
        int cs = (kk * 4 + q) ^ (m & 7);
        af[mi] = *(const half8*)(As + (m * 8 + cs) * 16);
      }
#pragma unroll
      for (int ni = 0; ni < NI; ++ni) {
        int n = wn * (BN / 2) + ni * 16 + ml;
        int cs = (kk * 4 + q) ^ (n & 7);
        bfv[ni] = *(const half8*)(Bs + (n * 8 + cs) * 16);
      }
#pragma unroll
      for (int mi = 0; mi < 4; ++mi)
#pragma unroll
        for (int ni = 0; ni < NI; ++ni)
          acc[mi][ni] = __builtin_amdgcn_mfma_f32_16x16x32_f16(af[mi], bfv[ni], acc[mi][ni], 0, 0, 0);
    }
    __syncthreads();
  }
#pragma unroll
  for (int mi = 0; mi < 4; ++mi)
#pragma unroll
    for (int ni = 0; ni < NI; ++ni)
#pragma unroll
      for (int r = 0; r < 4; ++r) {
        int b = b0 + wm * 64 + mi * 16 + q * 4 + r;
        int o = o0 + wn * (BN / 2) + ni * 16 + ml;
        float v = acc[mi][ni][r];
        out[(long)b * N + o] = v / (1.0f + __expf(-v));  // silu
      }
}

// ------- spline GEMM with ON-THE-FLY bases: act[M][I] fp16, swb[I][N][8] fp16 --
// acc[b][o] = sum_i sum_g exp(-3.125 (x[b][i]-cent[g])^2) * sw[i][o][g]
// gaussian factorization: f_g = A * r^g * t_g,  u = x + 0.044
//   A = 2^(-4.508422 u^2), r = 2^(0.07213475 u), t_g = 2^(-2.885390e-4 g^2)
template<int BN>
__global__ __launch_bounds__(256, (BN >= 256) ? 2 : 4) void spline_gemm_kernel(
    const short* __restrict__ act, const short* __restrict__ swb,
    const float* __restrict__ baseacc, const float* __restrict__ sb,
    const float* __restrict__ ss, float* __restrict__ outF,
    short* __restrict__ outH, int M, int N, int I) {
  constexpr int NI = BN / 32;
  __shared__ __align__(16) char smem[(128 + BN) * 8 * 16];
  char* As = smem;                 // slot (c, m): (c*128+m)*16 — 8 fp16 gaussians
  char* Bs = smem + 128 * 8 * 16;  // slot (c, n): (c*BN+n)*16
  const int lane = threadIdx.x & 63, wave = threadIdx.x >> 6;
  const int wm = wave & 1, wn = wave >> 1;
  const int b0 = blockIdx.x * 128, o0 = blockIdx.y * BN;
  const int ml = lane & 15, q = lane >> 4;
  const int am = threadIdx.x >> 1, ah = threadIdx.x & 1;   // A-staging: row, half
  const short* arow = act + (long)(b0 + am) * I + ah * 4;
  floatx4 acc[4][NI] = {};

  for (int i0 = 0; i0 < I; i0 += 8) {
    // B: async16 staging from swb (sw is [I][N][8] -> 16B chunk per (i,n))
#pragma unroll
    for (int j = 0; j < NI; ++j) {
      int lin = wave * (BN * 2) + j * 64;   // wave-uniform base
      int c = lin / BN, n0 = lin % BN;
      const short* g = swb + ((long)(i0 + c) * N + o0 + n0 + lane) * 8;
      async16(g, Bs + lin * 16);
    }
    // A: load 4 fp16 x-values, factorized gaussians, pack with pkrtz
    union { uint2 u; _Float16 h[4]; } cv;
    cv.u = *(const uint2*)(arow + i0);
#pragma unroll
    for (int cl = 0; cl < 4; ++cl) {
      int c = ah * 4 + cl;
      float u_ = (float)cv.h[cl] + 0.044f;
      float A = __builtin_exp2f(u_ * u_ * -4.508422f);
      float r = __builtin_exp2f(u_ * 0.07213475f);
      float f0 = A;
      float f1 = f0 * r * 0.99980003f;
      float f2 = f1 * r * 0.99940015f;
      float f3 = f2 * r * 0.99900046f;
      float f4 = f3 * r * 0.99860092f;
      float f5 = f4 * r * 0.99820155f;
      float f6 = f5 * r * 0.99780233f;
      float f7 = f6 * r * 0.99740327f;
      union { half8 v; fp16x2 p[4]; } pk;
      pk.p[0] = __builtin_amdgcn_cvt_pkrtz(f0, f1);
      pk.p[1] = __builtin_amdgcn_cvt_pkrtz(f2, f3);
      pk.p[2] = __builtin_amdgcn_cvt_pkrtz(f4, f5);
      pk.p[3] = __builtin_amdgcn_cvt_pkrtz(f6, f7);
      *(half8*)(As + (c * 128 + am) * 16) = pk.v;
    }
    __syncthreads();
#pragma unroll
    for (int kk = 0; kk < 2; ++kk) {
      half8 af[4], bfv[NI];
      int c = kk * 4 + q;
#pragma unroll
      for (int mi = 0; mi < 4; ++mi)
        af[mi] = *(const half8*)(As + (c * 128 + wm * 64 + mi * 16 + ml) * 16);
#pragma unroll
      for (int ni = 0; ni < NI; ++ni)
        bfv[ni] = *(const half8*)(Bs + (c * BN + wn * (BN / 2) + ni * 16 + ml) * 16);
#pragma unroll
      for (int mi = 0; mi < 4; ++mi)
#pragma unroll
        for (int ni = 0; ni < NI; ++ni)
          acc[mi][ni] = __builtin_amdgcn_mfma_f32_16x16x32_f16(af[mi], bfv[ni], acc[mi][ni], 0, 0, 0);
    }
    __syncthreads();
  }
#pragma unroll
  for (int mi = 0; mi < 4; ++mi)
#pragma unroll
    for (int ni = 0; ni < NI; ++ni)
#pragma unroll
      for (int r = 0; r < 4; ++r) {
        int b = b0 + wm * 64 + mi * 16 + q * 4 + r;
        int o = o0 + wn * (BN / 2) + ni * 16 + ml;
        long idx = (long)b * N + o;
        float v = baseacc[idx] * sb[o] + acc[mi][ni][r] * ss[o];
        if (outF) outF[idx] = v;
        if (outH) outH[idx] = f2h(v);
      }
}

extern "C" void kernel_launch(void* const* d_in, const int* in_sizes, int n_in,
                              void* d_out, int out_size, void* d_ws, size_t ws_size,
                              hipStream_t stream) {
  const int M = 8192;
  const int Is[4] = {1024, 2048, 256, 2048};
  const int Os[4] = {2048, 256, 2048, 1024};
  const float* x = (const float*)d_in[0];
  const float* sw[4]; const float* bw[4]; const float* sb[4]; const float* ssc[4];
  for (int l = 0; l < 4; ++l) {
    sw[l]  = (const float*)d_in[1 + 5 * l];
    bw[l]  = (const float*)d_in[2 + 5 * l];
    sb[l]  = (const float*)d_in[3 + 5 * l];
    ssc[l] = (const float*)d_in[4 + 5 * l];
  }
  char* ws = (char*)d_ws;
  size_t off = 0;
  auto alloc = [&](size_t bytes) {
    char* p = ws + off; off += (bytes + 255) & ~(size_t)255; return p;
  };
  short* swb[4]; short* bwT[4];
  for (int l = 0; l < 4; ++l) swb[l] = (short*)alloc((size_t)Is[l] * Os[l] * 8 * 2);
  for (int l = 0; l < 4; ++l) bwT[l] = (short*)alloc((size_t)Is[l] * Os[l] * 2);
  short* xhf = (short*)alloc((size_t)M * 1024 * 2);
  short* hb0 = (short*)alloc((size_t)M * 2048 * 2);
  short* zb  = (short*)alloc((size_t)M * 256 * 2);
  short* hb2 = (short*)alloc((size_t)M * 2048 * 2);
  float* bacc = (float*)alloc((size_t)M * 2048 * 4);
  (void)in_sizes; (void)n_in; (void)out_size;
  if (off > ws_size) return;  // fail readable (absmax) instead of GPU fault

  // prep: cast sw to fp16 (layout preserved), transpose-cast bw, cast x
  for (int l = 0; l < 4; ++l) {
    long n = (long)Is[l] * Os[l] * 8;
    cast_f16_kernel<<<(int)(n / 2048), 256, 0, stream>>>(sw[l], swb[l], n);
    transpose_cast_kernel<<<dim3(Is[l] / 32, Os[l] / 32), 256, 0, stream>>>(bw[l], bwT[l], Is[l], Os[l]);
  }
  cast_f16_kernel<<<(int)((long)M * 1024 / 2048), 256, 0, stream>>>(x, xhf, (long)M * 1024);

  float* xrec = (float*)d_out;
  float* zout = (float*)d_out + (size_t)M * 1024;

  // layer 0: 1024 -> 2048  (spline BN=256: 512 blocks, 8x recompute)
  base_gemm_kernel<128><<<dim3(M / 128, 2048 / 128), 256, 0, stream>>>(xhf, bwT[0], bacc, M, 2048, 1024);
  spline_gemm_kernel<256><<<dim3(M / 128, 2048 / 256), 256, 0, stream>>>(xhf, swb[0], bacc, sb[0], ssc[0], nullptr, hb0, M, 2048, 1024);

  // layer 1: 2048 -> 256 (BN=64 -> 256 blocks cover all CUs)
  base_gemm_kernel<64><<<dim3(M / 128, 256 / 64), 256, 0, stream>>>(hb0, bwT[1], bacc, M, 256, 2048);
  spline_gemm_kernel<64><<<dim3(M / 128, 256 / 64), 256, 0, stream>>>(hb0, swb[1], bacc, sb[1], ssc[1], zout, zb, M, 256, 2048);

  // layer 2: 256 -> 2048  (spline BN=256)
  base_gemm_kernel<128><<<dim3(M / 128, 2048 / 128), 256, 0, stream>>>(zb, bwT[2], bacc, M, 2048, 256);
  spline_gemm_kernel<256><<<dim3(M / 128, 2048 / 256), 256, 0, stream>>>(zb, swb[2], bacc, sb[2], ssc[2], nullptr, hb2, M, 2048, 256);

  // layer 3: 2048 -> 1024  (BN=128 keeps 512 blocks = 2/CU)
  base_gemm_kernel<128><<<dim3(M / 128, 1024 / 128), 256, 0, stream>>>(hb2, bwT[3], bacc, M, 1024, 2048);
  spline_gemm_kernel<128><<<dim3(M / 128, 1024 / 128), 256, 0, stream>>>(hb2, swb[3], bacc, sb[3], ssc[3], xrec, nullptr, M, 1024, 2048);
}